// Round 6
// baseline (320.350 us; speedup 1.0000x reference)
//
#include <hip/hip_runtime.h>
#include <hip/hip_fp16.h>

#define FDIM 128
#define HEADS 4
#define CD 32
#define BM 64
#define NBKT 256        // coarse destination buckets
#define CHUNK 256       // edges per chunk (= hist/eplace block)
#define SSUB 4          // sub-blocks per bucket in aggregate
#define MAXNL 200       // max nodes per bucket (ceil(50000/256)=196)

typedef __attribute__((ext_vector_type(8))) short bfrag;   // 8 bf16 (4 VGPRs)
typedef __attribute__((ext_vector_type(4))) float ffrag;   // 4 f32 accum

static __device__ __forceinline__ unsigned short f2bf(float v) {
    unsigned u = __float_as_uint(v);
    u += 0x7FFF + ((u >> 16) & 1);          // round-nearest-even
    return (unsigned short)(u >> 16);
}
static __device__ __forceinline__ float bf2f(unsigned short u) {
    return __uint_as_float(((unsigned)u) << 16);
}

// K0: split W into bf16 hi/lo, transpose to [n][k].
__global__ __launch_bounds__(256) void k_wsplit(const float* __restrict__ w,
                                                unsigned short* __restrict__ wt_hi,
                                                unsigned short* __restrict__ wt_lo)
{
    int i = blockIdx.x * 256 + threadIdx.x;
    float v = w[i];
    unsigned short h = f2bf(v);
    float r = v - bf2f(h);
    int k = i >> 7, n = i & 127;
    wt_hi[n * FDIM + k] = h;
    wt_lo[n * FDIM + k] = f2bf(r);
}

// K0b: per-chunk x bucket histogram of destinations. LDS atomics only;
// cnt[chunk][b] written coalesced (no global RMW).
__global__ __launch_bounds__(256) void k_hist(const int* __restrict__ ei, int E, int N,
                                              int* __restrict__ cnt)
{
    __shared__ int h[NBKT];
    int t = threadIdx.x, chunk = blockIdx.x;
    h[t] = 0;
    __syncthreads();
    int e = chunk * CHUNK + t;
    if (e < E) atomicAdd(&h[(ei[E + e] * NBKT) / N], 1);
    __syncthreads();
    cnt[chunk * NBKT + t] = h[t];
}

// K0c: per-bucket exclusive scan across chunks. Block b scans cnt[*][b] ->
// boff[b][*] (contiguous writes); bucket total -> btot[b].
__global__ __launch_bounds__(256) void k_scanA(const int* __restrict__ cnt,
                                               int* __restrict__ boff,
                                               int* __restrict__ btot, int nch)
{
    __shared__ int ws[4];
    int t = threadIdx.x, lane = t & 63, w = t >> 6, b = blockIdx.x;
    int carry = 0;
    for (int c0 = 0; c0 < nch; c0 += 256) {
        int idx = c0 + t;
        int v = (idx < nch) ? cnt[idx * NBKT + b] : 0;
        int x = v;
#pragma unroll
        for (int d = 1; d < 64; d <<= 1) { int y = __shfl_up(x, d, 64); if (lane >= d) x += y; }
        if (lane == 63) ws[w] = x;
        __syncthreads();
        int woff = 0;
        for (int i = 0; i < w; i++) woff += ws[i];
        int tot = ws[0] + ws[1] + ws[2] + ws[3];
        if (idx < nch) boff[b * nch + idx] = carry + woff + (x - v);
        carry += tot;
        __syncthreads();
    }
    if (t == 0) btot[b] = carry;
}

// K0d: exclusive scan of 256 bucket totals -> bbase[257].
__global__ __launch_bounds__(256) void k_scanB(const int* __restrict__ btot,
                                               int* __restrict__ bbase, int E)
{
    __shared__ int ws[4];
    int t = threadIdx.x, lane = t & 63, w = t >> 6;
    int v = btot[t];
    int x = v;
#pragma unroll
    for (int d = 1; d < 64; d <<= 1) { int y = __shfl_up(x, d, 64); if (lane >= d) x += y; }
    if (lane == 63) ws[w] = x;
    __syncthreads();
    int woff = 0;
    for (int i = 0; i < w; i++) woff += ws[i];
    bbase[t] = woff + (x - v);
    if (t == 255) bbase[256] = E;
}

// K1: MFMA GEMM (split bf16) + logits. Unchanged except prologue zeroes seg only.
__global__ __launch_bounds__(256) void k_gemm(const float* __restrict__ x,
                                              const unsigned short* __restrict__ wt_hi,
                                              const unsigned short* __restrict__ wt_lo,
                                              const float* __restrict__ att,
                                              unsigned short* __restrict__ xwh,
                                              float* __restrict__ a_src,
                                              float* __restrict__ a_dst,
                                              float4* __restrict__ zero_base,
                                              int nz4, int N)
{
    __shared__ float accs[BM * 132];
    __shared__ float attl[HEADS * 2 * CD];
    int t = threadIdx.x;
    int row0 = blockIdx.x * BM;
    for (int i = blockIdx.x * 256 + t; i < nz4; i += gridDim.x * 256)
        zero_base[i] = make_float4(0.f, 0.f, 0.f, 0.f);
    attl[t] = att[t];

    int l = t & 63, wv = t >> 6;
    int la = l & 15, lr = l >> 4;
    int arow = row0 + wv * 16 + la;
    bool aval = arow < N;
    const float* xbase = x + (size_t)arow * FDIM + lr * 8;

    ffrag acc[8] = {};
#pragma unroll
    for (int ks = 0; ks < 4; ks++) {
        float xv[8] = {0.f, 0.f, 0.f, 0.f, 0.f, 0.f, 0.f, 0.f};
        if (aval) {
            float4 f0 = *(const float4*)(xbase + ks * 32);
            float4 f1 = *(const float4*)(xbase + ks * 32 + 4);
            xv[0] = f0.x; xv[1] = f0.y; xv[2] = f0.z; xv[3] = f0.w;
            xv[4] = f1.x; xv[5] = f1.y; xv[6] = f1.z; xv[7] = f1.w;
        }
        bfrag ah, al;
#pragma unroll
        for (int j = 0; j < 8; j++) {
            unsigned short h = f2bf(xv[j]);
            ah[j] = (short)h;
            al[j] = (short)f2bf(xv[j] - bf2f(h));
        }
        int boffk = ks * 32 + lr * 8;
#pragma unroll
        for (int ct = 0; ct < 8; ct++) {
            int o = (ct * 16 + la) * FDIM + boffk;
            bfrag bh = *(const bfrag*)(wt_hi + o);
            bfrag bl = *(const bfrag*)(wt_lo + o);
            acc[ct] = __builtin_amdgcn_mfma_f32_16x16x32_bf16(ah, bh, acc[ct], 0, 0, 0);
            acc[ct] = __builtin_amdgcn_mfma_f32_16x16x32_bf16(ah, bl, acc[ct], 0, 0, 0);
            acc[ct] = __builtin_amdgcn_mfma_f32_16x16x32_bf16(al, bh, acc[ct], 0, 0, 0);
        }
    }

#pragma unroll
    for (int i = 0; i < 4; i++) {
        int r = row0 + wv * 16 + lr * 4 + i;
        if (r < N) {
            uint2 pa, pb;
            pa.x = (unsigned)f2bf(acc[0][i]) | ((unsigned)f2bf(acc[2][i]) << 16);
            pa.y = (unsigned)f2bf(acc[4][i]) | ((unsigned)f2bf(acc[6][i]) << 16);
            pb.x = (unsigned)f2bf(acc[1][i]) | ((unsigned)f2bf(acc[3][i]) << 16);
            pb.y = (unsigned)f2bf(acc[5][i]) | ((unsigned)f2bf(acc[7][i]) << 16);
            *(uint2*)&xwh[(size_t)r * FDIM + la * 4] = pa;
            *(uint2*)&xwh[(size_t)r * FDIM + 64 + la * 4] = pb;
        }
    }
#pragma unroll
    for (int ct = 0; ct < 8; ct++)
#pragma unroll
        for (int i = 0; i < 4; i++)
            accs[(wv * 16 + lr * 4 + i) * 132 + ct * 16 + la] = acc[ct][i];
    __syncthreads();
    int row = t >> 2, h = t & 3;
    const float* ap = &attl[h * 2 * CD];
    const float* xr = &accs[row * 132 + h * CD];
    float s = 0.f, d = 0.f;
#pragma unroll 8
    for (int c = 0; c < CD; c++) { float v = xr[c]; s += v * ap[c]; d += v * ap[CD + c]; }
    int n = row0 + row;
    if (n < N) { a_src[n * 4 + h] = s; a_dst[n * 4 + h] = d; }
}

// K2: merged esum+place. Lane-per-(edge,head): coalesced 16B-sector seg atomic
// (the ONLY global RMWs left); deterministic bucket placement via LDS ranks.
// rec = (r, cl, exp01 fp16, exp23 fp16) — RAW exp, normalized in aggregate.
__global__ __launch_bounds__(256) void k_eplace(const int* __restrict__ ei, int E, int N,
                                                const float* __restrict__ a_src,
                                                const float* __restrict__ a_dst,
                                                float* __restrict__ seg,
                                                const int* __restrict__ boff,
                                                const int* __restrict__ bbase,
                                                unsigned* __restrict__ recs, int nch)
{
    __shared__ int sOff[NBKT];
    __shared__ int lcnt[NBKT];
    int t = threadIdx.x, chunk = blockIdx.x;
    sOff[t] = bbase[t] + boff[t * nch + chunk];
    lcnt[t] = 0;
    __syncthreads();
    int lane = t & 63, h = t & 3, gl = lane & ~3;
#pragma unroll
    for (int j = 0; j < CHUNK / 64; j++) {
        int e = chunk * CHUNK + j * 64 + (t >> 2);
        if (e < E) {
            int r = ei[e], cl = ei[E + e];
            float a = a_src[r * 4 + h] + a_dst[cl * 4 + h];
            a = a >= 0.f ? a : 0.2f * a;
            float ex = __expf(a);
            atomicAdd(&seg[r * 4 + h], ex);
            float e0 = __shfl(ex, gl + 0, 64);
            float e1 = __shfl(ex, gl + 1, 64);
            float e2 = __shfl(ex, gl + 2, 64);
            float e3 = __shfl(ex, gl + 3, 64);
            __half2 h01 = __floats2half2_rn(e0, e1);
            __half2 h23 = __floats2half2_rn(e2, e3);
            int pos = 0;
            if (h == 0) {
                int b2 = (cl * NBKT) / N;
                pos = sOff[b2] + atomicAdd(&lcnt[b2], 1);
            }
            pos = __shfl(pos, gl, 64);
            unsigned val = (h == 0) ? (unsigned)r
                         : (h == 1) ? (unsigned)cl
                         : (h == 2) ? *(unsigned*)&h01 : *(unsigned*)&h23;
            recs[(size_t)pos * 4 + h] = val;
        }
    }
}

// K3: per-bucket aggregation, fp32 in LDS, ZERO global atomics. Bucket b holds
// nodes [ceil(bN/256), ceil((b+1)N/256)) <= 196. SSUB sub-blocks per bucket,
// each writes an fp32 partial; 16 lanes/edge gather the 256B xwh row.
__global__ __launch_bounds__(256) void k_aggregate(const unsigned* __restrict__ recs,
                                                   const int* __restrict__ bbase,
                                                   const unsigned short* __restrict__ xwh,
                                                   const float* __restrict__ seg,
                                                   float* __restrict__ out_part, int N)
{
    __shared__ float lacc[MAXNL * 32];
    int t = threadIdx.x;
    int b = blockIdx.x >> 2, s = blockIdx.x & 3;
    int ln0 = (b * N + NBKT - 1) / NBKT;
    int ln1 = ((b + 1) * N + NBKT - 1) / NBKT;
    int NL = ln1 - ln0;
    for (int i = t; i < NL * 32; i += 256) lacc[i] = 0.f;
    __syncthreads();
    int lo = bbase[b], hi = bbase[b + 1];
    int le = t >> 4, c2 = t & 15;
    for (int i = lo + s * 16 + le; i < hi; i += 64) {
        uint4 rec = ((const uint4*)recs)[i];
        int r = (int)rec.x, cl = (int)rec.y;
        __half2 x01 = *(__half2*)&rec.z;
        __half2 x23 = *(__half2*)&rec.w;
        float4 sg = *(const float4*)&seg[r * 4];
        float na0 = 0.25f * __low2float(x01) / (sg.x + 1e-16f);
        float na1 = 0.25f * __high2float(x01) / (sg.y + 1e-16f);
        float na2 = 0.25f * __low2float(x23) / (sg.z + 1e-16f);
        float na3 = 0.25f * __high2float(x23) / (sg.w + 1e-16f);
        uint4 q = ((const uint4*)(xwh + (size_t)r * FDIM))[c2];
        float acc0 = na0 * bf2f((unsigned short)(q.x & 0xFFFF)) + na1 * bf2f((unsigned short)(q.x >> 16))
                   + na2 * bf2f((unsigned short)(q.y & 0xFFFF)) + na3 * bf2f((unsigned short)(q.y >> 16));
        float acc1 = na0 * bf2f((unsigned short)(q.z & 0xFFFF)) + na1 * bf2f((unsigned short)(q.z >> 16))
                   + na2 * bf2f((unsigned short)(q.w & 0xFFFF)) + na3 * bf2f((unsigned short)(q.w >> 16));
        int li = (cl - ln0) * 32 + c2 * 2;
        atomicAdd(&lacc[li], acc0);
        atomicAdd(&lacc[li + 1], acc1);
    }
    __syncthreads();
    float* op = out_part + (size_t)s * N * 32 + (size_t)ln0 * 32;
    for (int i = t; i < NL * 32; i += 256) op[i] = lacc[i];
}

// K4: out = sum of SSUB fp32 partials + bias.
__global__ void k_final(const float* __restrict__ out_part, const float4* __restrict__ bias,
                        float4* __restrict__ out, int N)
{
    int i = blockIdx.x * 256 + threadIdx.x;
    if (i >= N * 8) return;
    size_t stride = (size_t)N * 8;                 // float4 units per partial
    const float4* p = (const float4*)out_part;
    float4 a = p[i], b1 = p[i + stride], c = p[i + 2 * stride], d = p[i + 3 * stride];
    float4 bb = bias[i & 7];
    out[i] = make_float4(a.x + b1.x + c.x + d.x + bb.x,
                         a.y + b1.y + c.y + d.y + bb.y,
                         a.z + b1.z + c.z + d.z + bb.z,
                         a.w + b1.w + c.w + d.w + bb.w);
}

extern "C" void kernel_launch(void* const* d_in, const int* in_sizes, int n_in,
                              void* d_out, int out_size, void* d_ws, size_t ws_size,
                              hipStream_t stream)
{
    const float* x    = (const float*)d_in[0];
    const int*   ei   = (const int*)d_in[1];
    const float* w    = (const float*)d_in[2];
    const float* att  = (const float*)d_in[3];
    const float* bias = (const float*)d_in[4];
    float* out = (float*)d_out;
    int N = in_sizes[0] / FDIM;
    int E = in_sizes[1] / 2;
    int nch = (E + CHUNK - 1) / CHUNK;            // 3125 for E=800000

    // layout (16B aligned): out_part aliases cnt/boff/a_src/a_dst (dead by then)
    unsigned short* xwh = (unsigned short*)d_ws;              // N*128 bf16  (12.8 MB)
    uint4* recs  = (uint4*)(xwh + (size_t)N * FDIM);          // E*16B       (12.8 MB)
    float* seg   = (float*)(recs + (size_t)E);                // N*4 f32 (zeroed by gemm)
    unsigned short* wt_hi = (unsigned short*)(seg + (size_t)N * HEADS);
    unsigned short* wt_lo = wt_hi + FDIM * FDIM;
    int* btot  = (int*)(wt_lo + FDIM * FDIM);                 // 256
    int* bbase = btot + NBKT;                                 // 257 (+pad)
    int* cnt   = bbase + NBKT + 16;                           // nch*256 ints
    int* boff  = cnt + (size_t)nch * NBKT;                    // 256*nch ints
    float* a_src = (float*)(boff + (size_t)NBKT * nch);       // N*4 f32
    float* a_dst = a_src + (size_t)N * HEADS;                 // N*4 f32
    float* out_part = (float*)cnt;                            // SSUB*N*32 f32 (alias)

    k_wsplit<<<(FDIM * FDIM) / 256, 256, 0, stream>>>(w, wt_hi, wt_lo);
    k_hist<<<nch, 256, 0, stream>>>(ei, E, N, cnt);
    k_scanA<<<NBKT, 256, 0, stream>>>(cnt, boff, btot, nch);
    k_scanB<<<1, 256, 0, stream>>>(btot, bbase, E);
    k_gemm<<<(N + BM - 1) / BM, 256, 0, stream>>>(x, wt_hi, wt_lo, att, xwh, a_src, a_dst,
                                                  (float4*)seg, N, N);
    k_eplace<<<nch, 256, 0, stream>>>(ei, E, N, a_src, a_dst, seg, boff, bbase,
                                      (unsigned*)recs, nch);
    k_aggregate<<<NBKT * SSUB, 256, 0, stream>>>((const unsigned*)recs, bbase, xwh, seg,
                                                 out_part, N);
    k_final<<<(N * 8 + 255) / 256, 256, 0, stream>>>(out_part, (const float4*)bias,
                                                     (float4*)out, N);
}

// Round 7
// 220.268 us; speedup vs baseline: 1.4544x; 1.4544x over previous
//
#include <hip/hip_runtime.h>
#include <hip/hip_fp16.h>

#define FDIM 128
#define HEADS 4
#define CD 32
#define BM 64
#define NBKT 256        // source-node buckets
#define SSUB 4          // sub-blocks per bucket in k_seg
#define MAXNL 200       // max nodes per bucket (ceil(50000/256)=196)

typedef __attribute__((ext_vector_type(8))) short bfrag;   // 8 bf16 (4 VGPRs)
typedef __attribute__((ext_vector_type(4))) float ffrag;   // 4 f32 accum

static __device__ __forceinline__ unsigned short f2bf(float v) {
    unsigned u = __float_as_uint(v);
    u += 0x7FFF + ((u >> 16) & 1);          // round-nearest-even
    return (unsigned short)(u >> 16);
}
static __device__ __forceinline__ float bf2f(unsigned short u) {
    return __uint_as_float(((unsigned)u) << 16);
}

// K0: split W into bf16 hi/lo, transpose to [n][k].
__global__ __launch_bounds__(256) void k_wsplit(const float* __restrict__ w,
                                                unsigned short* __restrict__ wt_hi,
                                                unsigned short* __restrict__ wt_lo)
{
    int i = blockIdx.x * 256 + threadIdx.x;
    float v = w[i];
    unsigned short h = f2bf(v);
    float r = v - bf2f(h);
    int k = i >> 7, n = i & 127;
    wt_hi[n * FDIM + k] = h;
    wt_lo[n * FDIM + k] = f2bf(r);
}

// K0b: per-chunk x src-bucket histogram. LDS atomics only; cntT[b][chunk] scattered
// 4B stores (no global RMW).
__global__ __launch_bounds__(256) void k_hist(const int* __restrict__ ei, int E, int N,
                                              int* __restrict__ cntT, int nch)
{
    __shared__ int h[NBKT];
    int t = threadIdx.x, chunk = blockIdx.x;
    h[t] = 0;
    __syncthreads();
    int e = chunk * 256 + t;
    if (e < E) atomicAdd(&h[(ei[e] * NBKT) / N], 1);
    __syncthreads();
    cntT[t * nch + chunk] = h[t];
}

// K0c: block b: exclusive scan of cntT[b][*] (coalesced row) -> boffT[b][*]; total->btot.
__global__ __launch_bounds__(256) void k_scanA(const int* __restrict__ cntT,
                                               int* __restrict__ boffT,
                                               int* __restrict__ btot, int nch)
{
    __shared__ int ws[4];
    int t = threadIdx.x, lane = t & 63, w = t >> 6, b = blockIdx.x;
    int carry = 0;
    for (int c0 = 0; c0 < nch; c0 += 256) {
        int idx = c0 + t;
        int v = (idx < nch) ? cntT[b * nch + idx] : 0;
        int x = v;
#pragma unroll
        for (int d = 1; d < 64; d <<= 1) { int y = __shfl_up(x, d, 64); if (lane >= d) x += y; }
        if (lane == 63) ws[w] = x;
        __syncthreads();
        int woff = 0;
        for (int i = 0; i < w; i++) woff += ws[i];
        int tot = ws[0] + ws[1] + ws[2] + ws[3];
        if (idx < nch) boffT[b * nch + idx] = carry + woff + (x - v);
        carry += tot;
        __syncthreads();
    }
    if (t == 0) btot[b] = carry;
}

// K0d: exclusive scan of 256 bucket totals -> bbase[257].
__global__ __launch_bounds__(256) void k_scanB(const int* __restrict__ btot,
                                               int* __restrict__ bbase, int E)
{
    __shared__ int ws[4];
    int t = threadIdx.x, lane = t & 63, w = t >> 6;
    int v = btot[t];
    int x = v;
#pragma unroll
    for (int d = 1; d < 64; d <<= 1) { int y = __shfl_up(x, d, 64); if (lane >= d) x += y; }
    if (lane == 63) ws[w] = x;
    __syncthreads();
    int woff = 0;
    for (int i = 0; i < w; i++) woff += ws[i];
    bbase[t] = woff + (x - v);
    if (t == 255) bbase[256] = E;
}

// K0e: deterministic src-bucket placement (LDS rank only). rec = (r, cl) 8B.
__global__ __launch_bounds__(256) void k_place(const int* __restrict__ ei, int E, int N,
                                               const int* __restrict__ boffT,
                                               const int* __restrict__ bbase,
                                               uint2* __restrict__ recs, int nch)
{
    __shared__ int sOff[NBKT];
    __shared__ int lcnt[NBKT];
    int t = threadIdx.x, chunk = blockIdx.x;
    sOff[t] = bbase[t] + boffT[t * nch + chunk];
    lcnt[t] = 0;
    __syncthreads();
    int e = chunk * 256 + t;
    if (e < E) {
        int r = ei[e], cl = ei[E + e];
        int b = (r * NBKT) / N;
        int pos = sOff[b] + atomicAdd(&lcnt[b], 1);
        recs[pos] = make_uint2((unsigned)r, (unsigned)cl);
    }
}

// K1: MFMA GEMM (split bf16: hi*hi + hi*lo + lo*hi ~= fp32) + logits.
// Prologue zeroes out_acc2 (N*16 half2) via grid-stride.
__global__ __launch_bounds__(256) void k_gemm(const float* __restrict__ x,
                                              const unsigned short* __restrict__ wt_hi,
                                              const unsigned short* __restrict__ wt_lo,
                                              const float* __restrict__ att,
                                              unsigned short* __restrict__ xwh,
                                              float* __restrict__ a_src,
                                              float* __restrict__ a_dst,
                                              float4* __restrict__ zero_base,
                                              int nz4, int N)
{
    __shared__ float accs[BM * 132];
    __shared__ float attl[HEADS * 2 * CD];
    int t = threadIdx.x;
    int row0 = blockIdx.x * BM;
    for (int i = blockIdx.x * 256 + t; i < nz4; i += gridDim.x * 256)
        zero_base[i] = make_float4(0.f, 0.f, 0.f, 0.f);
    attl[t] = att[t];

    int l = t & 63, wv = t >> 6;
    int la = l & 15, lr = l >> 4;
    int arow = row0 + wv * 16 + la;
    bool aval = arow < N;
    const float* xbase = x + (size_t)arow * FDIM + lr * 8;

    ffrag acc[8] = {};
#pragma unroll
    for (int ks = 0; ks < 4; ks++) {
        float xv[8] = {0.f, 0.f, 0.f, 0.f, 0.f, 0.f, 0.f, 0.f};
        if (aval) {
            float4 f0 = *(const float4*)(xbase + ks * 32);
            float4 f1 = *(const float4*)(xbase + ks * 32 + 4);
            xv[0] = f0.x; xv[1] = f0.y; xv[2] = f0.z; xv[3] = f0.w;
            xv[4] = f1.x; xv[5] = f1.y; xv[6] = f1.z; xv[7] = f1.w;
        }
        bfrag ah, al;
#pragma unroll
        for (int j = 0; j < 8; j++) {
            unsigned short h = f2bf(xv[j]);
            ah[j] = (short)h;
            al[j] = (short)f2bf(xv[j] - bf2f(h));
        }
        int boffk = ks * 32 + lr * 8;
#pragma unroll
        for (int ct = 0; ct < 8; ct++) {
            int o = (ct * 16 + la) * FDIM + boffk;
            bfrag bh = *(const bfrag*)(wt_hi + o);
            bfrag bl = *(const bfrag*)(wt_lo + o);
            acc[ct] = __builtin_amdgcn_mfma_f32_16x16x32_bf16(ah, bh, acc[ct], 0, 0, 0);
            acc[ct] = __builtin_amdgcn_mfma_f32_16x16x32_bf16(ah, bl, acc[ct], 0, 0, 0);
            acc[ct] = __builtin_amdgcn_mfma_f32_16x16x32_bf16(al, bh, acc[ct], 0, 0, 0);
        }
    }

#pragma unroll
    for (int i = 0; i < 4; i++) {
        int r = row0 + wv * 16 + lr * 4 + i;
        if (r < N) {
            uint2 pa, pb;
            pa.x = (unsigned)f2bf(acc[0][i]) | ((unsigned)f2bf(acc[2][i]) << 16);
            pa.y = (unsigned)f2bf(acc[4][i]) | ((unsigned)f2bf(acc[6][i]) << 16);
            pb.x = (unsigned)f2bf(acc[1][i]) | ((unsigned)f2bf(acc[3][i]) << 16);
            pb.y = (unsigned)f2bf(acc[5][i]) | ((unsigned)f2bf(acc[7][i]) << 16);
            *(uint2*)&xwh[(size_t)r * FDIM + la * 4] = pa;
            *(uint2*)&xwh[(size_t)r * FDIM + 64 + la * 4] = pb;
        }
    }
#pragma unroll
    for (int ct = 0; ct < 8; ct++)
#pragma unroll
        for (int i = 0; i < 4; i++)
            accs[(wv * 16 + lr * 4 + i) * 132 + ct * 16 + la] = acc[ct][i];
    __syncthreads();
    int row = t >> 2, h = t & 3;
    const float* ap = &attl[h * 2 * CD];
    const float* xr = &accs[row * 132 + h * CD];
    float s = 0.f, d = 0.f;
#pragma unroll 8
    for (int c = 0; c < CD; c++) { float v = xr[c]; s += v * ap[c]; d += v * ap[CD + c]; }
    int n = row0 + row;
    if (n < N) { a_src[n * 4 + h] = s; a_dst[n * 4 + h] = d; }
}

// K2: seg sums with ZERO global atomics. Block (bucket b, sub s): loop the bucket's
// src-sorted records, 4 lanes/edge (heads); exp accumulated into LDS seg_local
// (<=196 nodes * 4 heads); fp32 partial written with plain coalesced stores.
__global__ __launch_bounds__(256) void k_seg(const uint2* __restrict__ recs,
                                             const int* __restrict__ bbase,
                                             const float* __restrict__ a_src,
                                             const float* __restrict__ a_dst,
                                             float* __restrict__ seg_part, int N)
{
    __shared__ float segl[MAXNL * 4];
    int t = threadIdx.x;
    int b = blockIdx.x >> 2, s = blockIdx.x & 3;
    int ln0 = (b * N + NBKT - 1) / NBKT;
    int ln1 = ((b + 1) * N + NBKT - 1) / NBKT;
    int NL = ln1 - ln0;
    for (int i = t; i < NL * 4; i += 256) segl[i] = 0.f;
    __syncthreads();
    int lo = bbase[b], hi = bbase[b + 1];
    int slot = t >> 2, h = t & 3;
    for (int i = lo + s * 64 + slot; i < hi; i += 4 * 64) {
        uint2 rec = recs[i];
        int r = (int)rec.x, cl = (int)rec.y;
        float a = a_src[r * 4 + h] + a_dst[cl * 4 + h];
        a = a >= 0.f ? a : 0.2f * a;
        atomicAdd(&segl[(r - ln0) * 4 + h], __expf(a));
    }
    __syncthreads();
    float* op = seg_part + ((size_t)s * N + ln0) * 4;
    for (int i = t; i < NL * 4; i += 256) op[i] = segl[i];
}

// K3: fold SSUB partials; store sinv = 0.25/(sum+eps) (head-mean + softmax denom).
__global__ void k_segsum(const float* __restrict__ sp, float* __restrict__ sinv, int N)
{
    int i = blockIdx.x * 256 + threadIdx.x;
    if (i >= N * 4) return;
    size_t st = (size_t)N * 4;
    float s = sp[i] + sp[st + i] + sp[2 * st + i] + sp[3 * st + i];
    sinv[i] = 0.25f / (s + 1e-16f);
}

// K4: atomic scatter (THE wall, paid once). Reads src-sorted recs -> xwh gather is
// near-sequential; alpha recomputed from L2-resident a_src/a_dst * sinv.
__global__ __launch_bounds__(256) void k_scatter(const uint2* __restrict__ recs,
                                                 const float* __restrict__ a_src,
                                                 const float* __restrict__ a_dst,
                                                 const float* __restrict__ sinv,
                                                 const unsigned short* __restrict__ xwh,
                                                 __half2* __restrict__ out_acc2, int E)
{
    int t = threadIdx.x;
    int le = t >> 4, c2 = t & 15, lane = t & 63;   // 16 edges/block
    int idx = blockIdx.x * 16 + le;
    if (idx >= E) return;
    uint2 rec = recs[idx];
    int r = (int)rec.x, cl = (int)rec.y;
    float av = 0.f;
    if (c2 < 4) {
        float a = a_src[r * 4 + c2] + a_dst[cl * 4 + c2];
        a = a >= 0.f ? a : 0.2f * a;
        av = __expf(a) * sinv[r * 4 + c2];
    }
    uint4 q = ((const uint4*)(xwh + (size_t)r * FDIM))[c2];
    float a0 = __shfl(av, (lane & 48) + 0, 64);
    float a1 = __shfl(av, (lane & 48) + 1, 64);
    float a2 = __shfl(av, (lane & 48) + 2, 64);
    float a3 = __shfl(av, (lane & 48) + 3, 64);
    float v0 = a0 * bf2f((unsigned short)(q.x & 0xFFFF)) + a1 * bf2f((unsigned short)(q.x >> 16))
             + a2 * bf2f((unsigned short)(q.y & 0xFFFF)) + a3 * bf2f((unsigned short)(q.y >> 16));
    float v1 = a0 * bf2f((unsigned short)(q.z & 0xFFFF)) + a1 * bf2f((unsigned short)(q.z >> 16))
             + a2 * bf2f((unsigned short)(q.w & 0xFFFF)) + a3 * bf2f((unsigned short)(q.w >> 16));
    unsafeAtomicAdd(&out_acc2[(size_t)cl * 16 + c2], __floats2half2_rn(v0, v1));
}

// K5: out = fp16 out_acc2 + bias
__global__ void k_final(const __half2* __restrict__ out_acc2, const float4* __restrict__ bias,
                        float4* __restrict__ out, int N)
{
    int i = blockIdx.x * 256 + threadIdx.x;
    if (i >= N * 8) return;
    float4 b = bias[i & 7];
    float2 f0 = __half22float2(out_acc2[i * 2]);
    float2 f1 = __half22float2(out_acc2[i * 2 + 1]);
    out[i] = make_float4(f0.x + b.x, f0.y + b.y, f1.x + b.z, f1.y + b.w);
}

extern "C" void kernel_launch(void* const* d_in, const int* in_sizes, int n_in,
                              void* d_out, int out_size, void* d_ws, size_t ws_size,
                              hipStream_t stream)
{
    const float* x    = (const float*)d_in[0];
    const int*   ei   = (const int*)d_in[1];
    const float* w    = (const float*)d_in[2];
    const float* att  = (const float*)d_in[3];
    const float* bias = (const float*)d_in[4];
    float* out = (float*)d_out;
    int N = in_sizes[0] / FDIM;
    int E = in_sizes[1] / 2;
    int nch = (E + 255) / 256;                    // 3125 for E=800000

    // layout (16B aligned)
    unsigned short* xwh = (unsigned short*)d_ws;              // N*128 bf16  (12.8 MB)
    uint2* recs  = (uint2*)(xwh + (size_t)N * FDIM);          // E*8B src-sorted (6.4 MB)
    float* a_src = (float*)(recs + (size_t)E);                // N*4 f32
    float* a_dst = a_src + (size_t)N * HEADS;                 // N*4 f32
    float* sinv  = a_dst + (size_t)N * HEADS;                 // N*4 f32
    float* seg_part = sinv + (size_t)N * HEADS;               // SSUB*N*4 f32 (3.2 MB)
    __half2* out_acc2 = (__half2*)(seg_part + (size_t)SSUB * N * HEADS); // N*16 half2 (zeroed)
    unsigned short* wt_hi = (unsigned short*)(out_acc2 + (size_t)N * 16);
    unsigned short* wt_lo = wt_hi + FDIM * FDIM;
    int* btot  = (int*)(wt_lo + FDIM * FDIM);                 // 256
    int* bbase = btot + NBKT;                                 // 257 (+pad)
    int* cntT  = bbase + NBKT + 8;                            // 256*nch ints
    int* boffT = cntT + (size_t)NBKT * nch;                   // 256*nch ints

    int nz4 = N * 4;   // out_acc2: N*16 half2 = N*4 float4 units

    k_wsplit<<<(FDIM * FDIM) / 256, 256, 0, stream>>>(w, wt_hi, wt_lo);
    k_hist<<<nch, 256, 0, stream>>>(ei, E, N, cntT, nch);
    k_scanA<<<NBKT, 256, 0, stream>>>(cntT, boffT, btot, nch);
    k_scanB<<<1, 256, 0, stream>>>(btot, bbase, E);
    k_place<<<nch, 256, 0, stream>>>(ei, E, N, boffT, bbase, recs, nch);
    k_gemm<<<(N + BM - 1) / BM, 256, 0, stream>>>(x, wt_hi, wt_lo, att, xwh, a_src, a_dst,
                                                  (float4*)out_acc2, nz4, N);
    k_seg<<<NBKT * SSUB, 256, 0, stream>>>(recs, bbase, a_src, a_dst, seg_part, N);
    k_segsum<<<(N * HEADS + 255) / 256, 256, 0, stream>>>(seg_part, sinv, N);
    k_scatter<<<(E + 15) / 16, 256, 0, stream>>>(recs, a_src, a_dst, sinv, xwh, out_acc2, E);
    k_final<<<(N * 8 + 255) / 256, 256, 0, stream>>>(out_acc2, (const float4*)bias,
                                                     (float4*)out, N);
}